// Round 7
// baseline (89.151 us; speedup 1.0000x reference)
//
#include <hip/hip_runtime.h>
#include <math.h>

// Alignment (Kabsch):
//   H[b] = fx[b]^T fy[b]  (3x3, reduce over C=1024 points)
//   R[b] = (U Vh)^T == transpose of orthogonal polar factor of H[b]
//   S[b][d] = ||fy[b,:,d]|| / ||fx[b,:,d]||
//
// reduce_kernel: one WAVE per batch, NO LDS. Lane-interleaved float3 loads:
// lane l, iter it reads point (64*it + l) as global_load_dwordx3 (12 B).
// Wave footprint per instruction = 768 contiguous bytes -> 12 fully-consumed
// 64B lines (100% line utilization), unlike R1's lane-blocked float4 scheme
// (25%). 16 iters x (2 loads + 15 FMAs); wave shuffle-reduce; lane 0 writes
// 15 partials to ws. High occupancy (launch_bounds 8 waves/SIMD) provides
// all the latency hiding needed (Little's law: ~9 KB/CU in flight suffices).
// solve_kernel: one THREAD per batch, f64 scaled-Newton polar iteration
// (== v @ u^T from SVD for invertible H), writes R and S.

namespace {
constexpr int THREADS = 256;              // 4 waves = 4 batches per block
constexpr int WAVES_PER_BLOCK = 4;
constexpr int FLOATS_PER_BATCH = 3072;    // 1024 points * 3
constexpr int BYTES_PER_ARR = 12288;      // 12 KB per batch per array
constexpr int WS_STRIDE = 16;
}

struct f3 { float x, y, z; };

__global__ __launch_bounds__(THREADS, 8)
void reduce_kernel(const float* __restrict__ fx,
                   const float* __restrict__ fy,
                   float* __restrict__ ws)
{
    const int wave = threadIdx.x >> 6;
    const int lane = threadIdx.x & 63;
    const int b = blockIdx.x * WAVES_PER_BLOCK + wave;

    const char* gx = (const char*)fx + (size_t)b * BYTES_PER_ARR + 12 * lane;
    const char* gy = (const char*)fy + (size_t)b * BYTES_PER_ARR + 12 * lane;

    // v[0..8] = H[d][e] (row-major); v[9..11]=sum fx^2; v[12..14]=sum fy^2
    float v[15];
#pragma unroll
    for (int i = 0; i < 15; ++i) v[i] = 0.0f;

#pragma unroll 4
    for (int it = 0; it < 16; ++it) {
        f3 X = *reinterpret_cast<const f3*>(gx + it * 768);
        f3 Y = *reinterpret_cast<const f3*>(gy + it * 768);
        v[0] += X.x * Y.x; v[1] += X.x * Y.y; v[2] += X.x * Y.z;
        v[3] += X.y * Y.x; v[4] += X.y * Y.y; v[5] += X.y * Y.z;
        v[6] += X.z * Y.x; v[7] += X.z * Y.y; v[8] += X.z * Y.z;
        v[9]  += X.x * X.x; v[10] += X.y * X.y; v[11] += X.z * X.z;
        v[12] += Y.x * Y.x; v[13] += Y.y * Y.y; v[14] += Y.z * Y.z;
    }

    // Wave-wide (64 lanes) tree reduction; no LDS, no barriers.
#pragma unroll
    for (int i = 0; i < 15; ++i) {
#pragma unroll
        for (int s = 32; s > 0; s >>= 1) v[i] += __shfl_down(v[i], s, 64);
    }

    if (lane == 0) {
        float* w = ws + (size_t)b * WS_STRIDE;
#pragma unroll
        for (int i = 0; i < 15; ++i) w[i] = v[i];
    }
}

__global__ __launch_bounds__(THREADS)
void solve_kernel(const float* __restrict__ ws,
                  float* __restrict__ out,
                  int batches)
{
    const int b = blockIdx.x * THREADS + threadIdx.x;
    if (b >= batches) return;

    const float4* w4 = reinterpret_cast<const float4*>(ws + (size_t)b * WS_STRIDE);
    float4 t0 = w4[0], t1 = w4[1], t2 = w4[2], t3 = w4[3];
    float tot[15] = {t0.x, t0.y, t0.z, t0.w, t1.x, t1.y, t1.z, t1.w,
                     t2.x, t2.y, t2.z, t2.w, t3.x, t3.y, t3.z};

    // ---- Polar decomposition of H (3x3) via scaled Newton, f64 ----
    double Q[9];
    double nf = 0.0;
#pragma unroll
    for (int i = 0; i < 9; ++i) { Q[i] = (double)tot[i]; nf += Q[i] * Q[i]; }
    double s0 = (nf > 0.0) ? 1.0 / sqrt(nf) : 1.0;
#pragma unroll
    for (int i = 0; i < 9; ++i) Q[i] *= s0;

    for (int it = 0; it < 8; ++it) {
        double C0 = Q[4] * Q[8] - Q[5] * Q[7];
        double C1 = Q[5] * Q[6] - Q[3] * Q[8];
        double C2 = Q[3] * Q[7] - Q[4] * Q[6];
        double C3 = Q[2] * Q[7] - Q[1] * Q[8];
        double C4 = Q[0] * Q[8] - Q[2] * Q[6];
        double C5 = Q[1] * Q[6] - Q[0] * Q[7];
        double C6 = Q[1] * Q[5] - Q[2] * Q[4];
        double C7 = Q[2] * Q[3] - Q[0] * Q[5];
        double C8 = Q[0] * Q[4] - Q[1] * Q[3];
        double det = Q[0] * C0 + Q[1] * C1 + Q[2] * C2;
        double ad = fabs(det);
        if (ad < 1e-300) { det = (det < 0.0) ? -1e-300 : 1e-300; ad = 1e-300; }
        double nq = Q[0]*Q[0]+Q[1]*Q[1]+Q[2]*Q[2]+Q[3]*Q[3]+Q[4]*Q[4]
                  + Q[5]*Q[5]+Q[6]*Q[6]+Q[7]*Q[7]+Q[8]*Q[8];
        double nc = C0*C0+C1*C1+C2*C2+C3*C3+C4*C4+C5*C5+C6*C6+C7*C7+C8*C8;
        double lam = sqrt(sqrt(nc) / (ad * sqrt(nq)));
        double hl = 0.5 * lam;
        double g  = 0.5 / (lam * det);
        double N0 = hl * Q[0] + g * C0;
        double N1 = hl * Q[1] + g * C1;
        double N2 = hl * Q[2] + g * C2;
        double N3 = hl * Q[3] + g * C3;
        double N4 = hl * Q[4] + g * C4;
        double N5 = hl * Q[5] + g * C5;
        double N6 = hl * Q[6] + g * C6;
        double N7 = hl * Q[7] + g * C7;
        double N8 = hl * Q[8] + g * C8;
        Q[0]=N0; Q[1]=N1; Q[2]=N2; Q[3]=N3; Q[4]=N4; Q[5]=N5; Q[6]=N6; Q[7]=N7; Q[8]=N8;
    }

    // R = Q^T (row-major [3][3])
    float* Rout = out + (size_t)b * 9;
    Rout[0] = (float)Q[0]; Rout[1] = (float)Q[3]; Rout[2] = (float)Q[6];
    Rout[3] = (float)Q[1]; Rout[4] = (float)Q[4]; Rout[5] = (float)Q[7];
    Rout[6] = (float)Q[2]; Rout[7] = (float)Q[5]; Rout[8] = (float)Q[8];

    // S[d] = sqrt(sum fy^2 / sum fx^2)
    float* Sout = out + (size_t)batches * 9 + (size_t)b * 3;
    Sout[0] = sqrtf(tot[12] / tot[9]);
    Sout[1] = sqrtf(tot[13] / tot[10]);
    Sout[2] = sqrtf(tot[14] / tot[11]);
}

extern "C" void kernel_launch(void* const* d_in, const int* in_sizes, int n_in,
                              void* d_out, int out_size, void* d_ws, size_t ws_size,
                              hipStream_t stream) {
    const float* fx = (const float*)d_in[0];
    const float* fy = (const float*)d_in[1];
    float* out = (float*)d_out;
    float* ws = (float*)d_ws;
    const int batches = in_sizes[0] / FLOATS_PER_BATCH;  // 16384

    reduce_kernel<<<batches / WAVES_PER_BLOCK, THREADS, 0, stream>>>(fx, fy, ws);
    solve_kernel<<<(batches + THREADS - 1) / THREADS, THREADS, 0, stream>>>(ws, out, batches);
}

// Round 9
// 85.166 us; speedup vs baseline: 1.0468x; 1.0468x over previous
//
#include <hip/hip_runtime.h>
#include <math.h>

// Alignment (Kabsch), FUSED single kernel:
//   H[b] = fx[b]^T fy[b]  (3x3, reduce over C=1024 points)
//   R[b] = (U Vh)^T == transpose of orthogonal polar factor of H[b]
//   S[b][d] = ||fy[b,:,d]|| / ||fx[b,:,d]||
//
// One WAVE per batch. Global->LDS staging in QUARTERS (256 points = 3 KB
// per array) via lane-contiguous global_load_lds dwordx4 (16 B/lane, wave
// footprint 1 KB contiguous = 16 fully-used 64B lines -- the m13 pattern,
// best timed variant R4=78.8us). Double-buffered, counted s_waitcnt
// vmcnt(6). Lane reads its 48 B (4 whole points) from LDS as 3x b128
// (48*lane is 16-aligned). Wave shuffle-reduce of 15 partials; lane 0 then
// solves the 3x3 polar factor in f64 (scaled Newton == v @ u^T from SVD)
// and writes R and S directly. No workspace, no second launch.

namespace {
constexpr int THREADS = 256;                 // 4 waves = 4 batches per block
constexpr int WAVES_PER_BLOCK = 4;
constexpr int FLOATS_PER_BATCH = 3072;       // 1024 points * 3
constexpr int BYTES_PER_ARR = 12288;         // 12 KB per batch per array
constexpr int QBYTES = 3072;                 // quarter: 256 points * 12 B
constexpr int LDS_PER_WAVE = 2 * 2 * QBYTES; // dbuf x {fx,fy} x 3 KB = 12 KB
}

__device__ inline void gload_lds16(const void* g, void* l) {
    __builtin_amdgcn_global_load_lds(
        (const __attribute__((address_space(1))) void*)g,
        (__attribute__((address_space(3))) void*)l,
        16, 0, 0);
}

__global__ __launch_bounds__(THREADS)
void align_kernel(const float* __restrict__ fx,
                  const float* __restrict__ fy,
                  float* __restrict__ out,
                  int batches)
{
    __shared__ char lds_raw[WAVES_PER_BLOCK * LDS_PER_WAVE];  // 48 KB
    const int wave = threadIdx.x >> 6;
    const int lane = threadIdx.x & 63;
    const int b = blockIdx.x * WAVES_PER_BLOCK + wave;

    char* my = lds_raw + wave * LDS_PER_WAVE;          // wave-private
    const char* gx = (const char*)fx + (size_t)b * BYTES_PER_ARR;
    const char* gy = (const char*)fy + (size_t)b * BYTES_PER_ARR;

    auto stage = [&](int q, int buf) {
#pragma unroll
        for (int s = 0; s < 3; ++s)
            gload_lds16(gx + q * QBYTES + s * 1024 + lane * 16,
                        my + buf * (2 * QBYTES) + s * 1024);
#pragma unroll
        for (int s = 0; s < 3; ++s)
            gload_lds16(gy + q * QBYTES + s * 1024 + lane * 16,
                        my + buf * (2 * QBYTES) + QBYTES + s * 1024);
    };

    // v[0..8] = H[d][e] (row-major); v[9..11]=sum fx^2; v[12..14]=sum fy^2
    float v[15];
#pragma unroll
    for (int i = 0; i < 15; ++i) v[i] = 0.0f;

    stage(0, 0);
#pragma unroll
    for (int q = 0; q < 4; ++q) {
        const int buf = q & 1;
        if (q < 3) stage(q + 1, buf ^ 1);
        __builtin_amdgcn_sched_barrier(0);
        if (q < 3) { asm volatile("s_waitcnt vmcnt(6)" ::: "memory"); }
        else       { asm volatile("s_waitcnt vmcnt(0)" ::: "memory"); }
        __builtin_amdgcn_sched_barrier(0);

        // Lane owns 4 points = 48 B of this quarter (16-aligned -> b128 ok).
        const float4* X4 = reinterpret_cast<const float4*>(my + buf * (2 * QBYTES) + 48 * lane);
        const float4* Y4 = reinterpret_cast<const float4*>(my + buf * (2 * QBYTES) + QBYTES + 48 * lane);
        float4 a0 = X4[0], a1 = X4[1], a2 = X4[2];
        float4 b0 = Y4[0], b1 = Y4[1], b2 = Y4[2];
        float X[12] = {a0.x, a0.y, a0.z, a0.w, a1.x, a1.y, a1.z, a1.w, a2.x, a2.y, a2.z, a2.w};
        float Y[12] = {b0.x, b0.y, b0.z, b0.w, b1.x, b1.y, b1.z, b1.w, b2.x, b2.y, b2.z, b2.w};
#pragma unroll
        for (int k = 0; k < 4; ++k) {
            float px0 = X[3 * k + 0], px1 = X[3 * k + 1], px2 = X[3 * k + 2];
            float py0 = Y[3 * k + 0], py1 = Y[3 * k + 1], py2 = Y[3 * k + 2];
            v[0] += px0 * py0; v[1] += px0 * py1; v[2] += px0 * py2;
            v[3] += px1 * py0; v[4] += px1 * py1; v[5] += px1 * py2;
            v[6] += px2 * py0; v[7] += px2 * py1; v[8] += px2 * py2;
            v[9]  += px0 * px0; v[10] += px1 * px1; v[11] += px2 * px2;
            v[12] += py0 * py0; v[13] += py1 * py1; v[14] += py2 * py2;
        }
    }

    // Wave-wide (64 lanes) tree reduction; no barriers.
#pragma unroll
    for (int i = 0; i < 15; ++i) {
#pragma unroll
        for (int s = 32; s > 0; s >>= 1) v[i] += __shfl_down(v[i], s, 64);
    }

    if (lane != 0) return;

    // ---- Polar decomposition of H (3x3) via scaled Newton, f64 (lane 0) ----
    double Q[9];
    double nf = 0.0;
#pragma unroll
    for (int i = 0; i < 9; ++i) { Q[i] = (double)v[i]; nf += Q[i] * Q[i]; }
    double s0 = (nf > 0.0) ? 1.0 / sqrt(nf) : 1.0;
#pragma unroll
    for (int i = 0; i < 9; ++i) Q[i] *= s0;

    for (int it = 0; it < 8; ++it) {
        double C0 = Q[4] * Q[8] - Q[5] * Q[7];
        double C1 = Q[5] * Q[6] - Q[3] * Q[8];
        double C2 = Q[3] * Q[7] - Q[4] * Q[6];
        double C3 = Q[2] * Q[7] - Q[1] * Q[8];
        double C4 = Q[0] * Q[8] - Q[2] * Q[6];
        double C5 = Q[1] * Q[6] - Q[0] * Q[7];
        double C6 = Q[1] * Q[5] - Q[2] * Q[4];
        double C7 = Q[2] * Q[3] - Q[0] * Q[5];
        double C8 = Q[0] * Q[4] - Q[1] * Q[3];
        double det = Q[0] * C0 + Q[1] * C1 + Q[2] * C2;
        double ad = fabs(det);
        if (ad < 1e-300) { det = (det < 0.0) ? -1e-300 : 1e-300; ad = 1e-300; }
        double nq = Q[0]*Q[0]+Q[1]*Q[1]+Q[2]*Q[2]+Q[3]*Q[3]+Q[4]*Q[4]
                  + Q[5]*Q[5]+Q[6]*Q[6]+Q[7]*Q[7]+Q[8]*Q[8];
        double nc = C0*C0+C1*C1+C2*C2+C3*C3+C4*C4+C5*C5+C6*C6+C7*C7+C8*C8;
        double lam = sqrt(sqrt(nc) / (ad * sqrt(nq)));
        double hl = 0.5 * lam;
        double g  = 0.5 / (lam * det);
        double N0 = hl * Q[0] + g * C0;
        double N1 = hl * Q[1] + g * C1;
        double N2 = hl * Q[2] + g * C2;
        double N3 = hl * Q[3] + g * C3;
        double N4 = hl * Q[4] + g * C4;
        double N5 = hl * Q[5] + g * C5;
        double N6 = hl * Q[6] + g * C6;
        double N7 = hl * Q[7] + g * C7;
        double N8 = hl * Q[8] + g * C8;
        Q[0]=N0; Q[1]=N1; Q[2]=N2; Q[3]=N3; Q[4]=N4; Q[5]=N5; Q[6]=N6; Q[7]=N7; Q[8]=N8;
    }

    // R = Q^T (row-major [3][3])
    float* Rout = out + (size_t)b * 9;
    Rout[0] = (float)Q[0]; Rout[1] = (float)Q[3]; Rout[2] = (float)Q[6];
    Rout[3] = (float)Q[1]; Rout[4] = (float)Q[4]; Rout[5] = (float)Q[7];
    Rout[6] = (float)Q[2]; Rout[7] = (float)Q[5]; Rout[8] = (float)Q[8];

    // S[d] = sqrt(sum fy^2 / sum fx^2)
    float* Sout = out + (size_t)batches * 9 + (size_t)b * 3;
    Sout[0] = sqrtf(v[12] / v[9]);
    Sout[1] = sqrtf(v[13] / v[10]);
    Sout[2] = sqrtf(v[14] / v[11]);
}

extern "C" void kernel_launch(void* const* d_in, const int* in_sizes, int n_in,
                              void* d_out, int out_size, void* d_ws, size_t ws_size,
                              hipStream_t stream) {
    const float* fx = (const float*)d_in[0];
    const float* fy = (const float*)d_in[1];
    float* out = (float*)d_out;
    const int batches = in_sizes[0] / FLOATS_PER_BATCH;  // 16384

    align_kernel<<<batches / WAVES_PER_BLOCK, THREADS, 0, stream>>>(fx, fy, out, batches);
}

// Round 11
// 78.157 us; speedup vs baseline: 1.1407x; 1.0897x over previous
//
#include <hip/hip_runtime.h>
#include <math.h>

// Alignment (Kabsch):
//   H[b] = fx[b]^T fy[b]  (3x3, reduce over C=1024 points)
//   R[b] = (U Vh)^T == transpose of orthogonal polar factor of H[b]
//   S[b][d] = ||fy[b,:,d]|| / ||fx[b,:,d]||
//
// reduce_kernel (R4 structure, best timed = 78.8us): one WAVE per batch.
// Global->LDS staging in QUARTERS (256 points = 3 KB per array) via
// lane-contiguous global_load_lds dwordx4 (16 B/lane, 1 KB contiguous wave
// footprint). Double-buffered, counted s_waitcnt vmcnt(6). Lane reads its
// 48 B (4 whole points, 16-aligned) from LDS as 3x b128. Wave
// shuffle-reduce of 15 partials; lane 0 writes to ws.
// solve_kernel: one THREAD per batch (64-lane-parallel chains — fusing this
// into the reduce wave's lane 0 was R9's regression). Hybrid precision:
// 5 f32 scaled-Newton iters + 2 f64 polish iters (self-correcting).

namespace {
constexpr int THREADS = 256;                 // 4 waves = 4 batches per block
constexpr int WAVES_PER_BLOCK = 4;
constexpr int FLOATS_PER_BATCH = 3072;       // 1024 points * 3
constexpr int BYTES_PER_ARR = 12288;         // 12 KB per batch per array
constexpr int QBYTES = 3072;                 // quarter: 256 points * 12 B
constexpr int LDS_PER_WAVE = 2 * 2 * QBYTES; // dbuf x {fx,fy} x 3 KB = 12 KB
constexpr int WS_STRIDE = 16;
}

__device__ inline void gload_lds16(const void* g, void* l) {
    __builtin_amdgcn_global_load_lds(
        (const __attribute__((address_space(1))) void*)g,
        (__attribute__((address_space(3))) void*)l,
        16, 0, 0);
}

__global__ __launch_bounds__(THREADS)
void reduce_kernel(const float* __restrict__ fx,
                   const float* __restrict__ fy,
                   float* __restrict__ ws)
{
    __shared__ char lds_raw[WAVES_PER_BLOCK * LDS_PER_WAVE];  // 48 KB
    const int wave = threadIdx.x >> 6;
    const int lane = threadIdx.x & 63;
    const int b = blockIdx.x * WAVES_PER_BLOCK + wave;

    char* my = lds_raw + wave * LDS_PER_WAVE;          // wave-private
    const char* gx = (const char*)fx + (size_t)b * BYTES_PER_ARR;
    const char* gy = (const char*)fy + (size_t)b * BYTES_PER_ARR;

    auto stage = [&](int q, int buf) {
#pragma unroll
        for (int s = 0; s < 3; ++s)
            gload_lds16(gx + q * QBYTES + s * 1024 + lane * 16,
                        my + buf * (2 * QBYTES) + s * 1024);
#pragma unroll
        for (int s = 0; s < 3; ++s)
            gload_lds16(gy + q * QBYTES + s * 1024 + lane * 16,
                        my + buf * (2 * QBYTES) + QBYTES + s * 1024);
    };

    // v[0..8] = H[d][e] (row-major); v[9..11]=sum fx^2; v[12..14]=sum fy^2
    float v[15];
#pragma unroll
    for (int i = 0; i < 15; ++i) v[i] = 0.0f;

    stage(0, 0);
#pragma unroll
    for (int q = 0; q < 4; ++q) {
        const int buf = q & 1;
        if (q < 3) stage(q + 1, buf ^ 1);
        __builtin_amdgcn_sched_barrier(0);
        if (q < 3) { asm volatile("s_waitcnt vmcnt(6)" ::: "memory"); }
        else       { asm volatile("s_waitcnt vmcnt(0)" ::: "memory"); }
        __builtin_amdgcn_sched_barrier(0);

        // Lane owns 4 points = 48 B of this quarter (16-aligned -> b128 ok).
        const float4* X4 = reinterpret_cast<const float4*>(my + buf * (2 * QBYTES) + 48 * lane);
        const float4* Y4 = reinterpret_cast<const float4*>(my + buf * (2 * QBYTES) + QBYTES + 48 * lane);
        float4 a0 = X4[0], a1 = X4[1], a2 = X4[2];
        float4 b0 = Y4[0], b1 = Y4[1], b2 = Y4[2];
        float X[12] = {a0.x, a0.y, a0.z, a0.w, a1.x, a1.y, a1.z, a1.w, a2.x, a2.y, a2.z, a2.w};
        float Y[12] = {b0.x, b0.y, b0.z, b0.w, b1.x, b1.y, b1.z, b1.w, b2.x, b2.y, b2.z, b2.w};
#pragma unroll
        for (int k = 0; k < 4; ++k) {
            float px0 = X[3 * k + 0], px1 = X[3 * k + 1], px2 = X[3 * k + 2];
            float py0 = Y[3 * k + 0], py1 = Y[3 * k + 1], py2 = Y[3 * k + 2];
            v[0] += px0 * py0; v[1] += px0 * py1; v[2] += px0 * py2;
            v[3] += px1 * py0; v[4] += px1 * py1; v[5] += px1 * py2;
            v[6] += px2 * py0; v[7] += px2 * py1; v[8] += px2 * py2;
            v[9]  += px0 * px0; v[10] += px1 * px1; v[11] += px2 * px2;
            v[12] += py0 * py0; v[13] += py1 * py1; v[14] += py2 * py2;
        }
    }

    // Wave-wide (64 lanes) tree reduction; no barriers.
#pragma unroll
    for (int i = 0; i < 15; ++i) {
#pragma unroll
        for (int s = 32; s > 0; s >>= 1) v[i] += __shfl_down(v[i], s, 64);
    }

    if (lane == 0) {
        float* w = ws + (size_t)b * WS_STRIDE;
#pragma unroll
        for (int i = 0; i < 15; ++i) w[i] = v[i];
    }
}

__global__ __launch_bounds__(THREADS)
void solve_kernel(const float* __restrict__ ws,
                  float* __restrict__ out,
                  int batches)
{
    const int b = blockIdx.x * THREADS + threadIdx.x;
    if (b >= batches) return;

    const float4* w4 = reinterpret_cast<const float4*>(ws + (size_t)b * WS_STRIDE);
    float4 t0 = w4[0], t1 = w4[1], t2 = w4[2], t3 = w4[3];
    float tot[15] = {t0.x, t0.y, t0.z, t0.w, t1.x, t1.y, t1.z, t1.w,
                     t2.x, t2.y, t2.z, t2.w, t3.x, t3.y, t3.z};

    // ---- Polar decomposition of H (3x3), scaled Newton ----
    // Phase 1: 5 iterations in f32 (cheap sqrt/div).
    float F[9];
    float nf32 = 0.0f;
#pragma unroll
    for (int i = 0; i < 9; ++i) { F[i] = tot[i]; nf32 += F[i] * F[i]; }
    float fs0 = (nf32 > 0.0f) ? 1.0f / sqrtf(nf32) : 1.0f;
#pragma unroll
    for (int i = 0; i < 9; ++i) F[i] *= fs0;

    for (int it = 0; it < 5; ++it) {
        float C0 = F[4] * F[8] - F[5] * F[7];
        float C1 = F[5] * F[6] - F[3] * F[8];
        float C2 = F[3] * F[7] - F[4] * F[6];
        float C3 = F[2] * F[7] - F[1] * F[8];
        float C4 = F[0] * F[8] - F[2] * F[6];
        float C5 = F[1] * F[6] - F[0] * F[7];
        float C6 = F[1] * F[5] - F[2] * F[4];
        float C7 = F[2] * F[3] - F[0] * F[5];
        float C8 = F[0] * F[4] - F[1] * F[3];
        float det = F[0] * C0 + F[1] * C1 + F[2] * C2;
        float ad = fabsf(det);
        if (ad < 1e-30f) { det = (det < 0.0f) ? -1e-30f : 1e-30f; ad = 1e-30f; }
        float nq = F[0]*F[0]+F[1]*F[1]+F[2]*F[2]+F[3]*F[3]+F[4]*F[4]
                 + F[5]*F[5]+F[6]*F[6]+F[7]*F[7]+F[8]*F[8];
        float nc = C0*C0+C1*C1+C2*C2+C3*C3+C4*C4+C5*C5+C6*C6+C7*C7+C8*C8;
        float lam = sqrtf(sqrtf(nc) / (ad * sqrtf(nq)));
        float hl = 0.5f * lam;
        float g  = 0.5f / (lam * det);
        float N0 = hl * F[0] + g * C0;
        float N1 = hl * F[1] + g * C1;
        float N2 = hl * F[2] + g * C2;
        float N3 = hl * F[3] + g * C3;
        float N4 = hl * F[4] + g * C4;
        float N5 = hl * F[5] + g * C5;
        float N6 = hl * F[6] + g * C6;
        float N7 = hl * F[7] + g * C7;
        float N8 = hl * F[8] + g * C8;
        F[0]=N0; F[1]=N1; F[2]=N2; F[3]=N3; F[4]=N4; F[5]=N5; F[6]=N6; F[7]=N7; F[8]=N8;
    }

    // Phase 2: 2 polish iterations in f64 (Newton is self-correcting).
    double Q[9];
#pragma unroll
    for (int i = 0; i < 9; ++i) Q[i] = (double)F[i];

    for (int it = 0; it < 2; ++it) {
        double C0 = Q[4] * Q[8] - Q[5] * Q[7];
        double C1 = Q[5] * Q[6] - Q[3] * Q[8];
        double C2 = Q[3] * Q[7] - Q[4] * Q[6];
        double C3 = Q[2] * Q[7] - Q[1] * Q[8];
        double C4 = Q[0] * Q[8] - Q[2] * Q[6];
        double C5 = Q[1] * Q[6] - Q[0] * Q[7];
        double C6 = Q[1] * Q[5] - Q[2] * Q[4];
        double C7 = Q[2] * Q[3] - Q[0] * Q[5];
        double C8 = Q[0] * Q[4] - Q[1] * Q[3];
        double det = Q[0] * C0 + Q[1] * C1 + Q[2] * C2;
        double ad = fabs(det);
        if (ad < 1e-300) { det = (det < 0.0) ? -1e-300 : 1e-300; ad = 1e-300; }
        double nq = Q[0]*Q[0]+Q[1]*Q[1]+Q[2]*Q[2]+Q[3]*Q[3]+Q[4]*Q[4]
                  + Q[5]*Q[5]+Q[6]*Q[6]+Q[7]*Q[7]+Q[8]*Q[8];
        double nc = C0*C0+C1*C1+C2*C2+C3*C3+C4*C4+C5*C5+C6*C6+C7*C7+C8*C8;
        double lam = sqrt(sqrt(nc) / (ad * sqrt(nq)));
        double hl = 0.5 * lam;
        double g  = 0.5 / (lam * det);
        double N0 = hl * Q[0] + g * C0;
        double N1 = hl * Q[1] + g * C1;
        double N2 = hl * Q[2] + g * C2;
        double N3 = hl * Q[3] + g * C3;
        double N4 = hl * Q[4] + g * C4;
        double N5 = hl * Q[5] + g * C5;
        double N6 = hl * Q[6] + g * C6;
        double N7 = hl * Q[7] + g * C7;
        double N8 = hl * Q[8] + g * C8;
        Q[0]=N0; Q[1]=N1; Q[2]=N2; Q[3]=N3; Q[4]=N4; Q[5]=N5; Q[6]=N6; Q[7]=N7; Q[8]=N8;
    }

    // R = Q^T (row-major [3][3])
    float* Rout = out + (size_t)b * 9;
    Rout[0] = (float)Q[0]; Rout[1] = (float)Q[3]; Rout[2] = (float)Q[6];
    Rout[3] = (float)Q[1]; Rout[4] = (float)Q[4]; Rout[5] = (float)Q[7];
    Rout[6] = (float)Q[2]; Rout[7] = (float)Q[5]; Rout[8] = (float)Q[8];

    // S[d] = sqrt(sum fy^2 / sum fx^2)
    float* Sout = out + (size_t)batches * 9 + (size_t)b * 3;
    Sout[0] = sqrtf(tot[12] / tot[9]);
    Sout[1] = sqrtf(tot[13] / tot[10]);
    Sout[2] = sqrtf(tot[14] / tot[11]);
}

extern "C" void kernel_launch(void* const* d_in, const int* in_sizes, int n_in,
                              void* d_out, int out_size, void* d_ws, size_t ws_size,
                              hipStream_t stream) {
    const float* fx = (const float*)d_in[0];
    const float* fy = (const float*)d_in[1];
    float* out = (float*)d_out;
    float* ws = (float*)d_ws;
    const int batches = in_sizes[0] / FLOATS_PER_BATCH;  // 16384

    reduce_kernel<<<batches / WAVES_PER_BLOCK, THREADS, 0, stream>>>(fx, fy, ws);
    solve_kernel<<<(batches + THREADS - 1) / THREADS, THREADS, 0, stream>>>(ws, out, batches);
}